// Round 7
// baseline (33.693 us; speedup 1.0000x reference)
//
#include <hip/hip_runtime.h>
#include <math.h>

#define EPS_T 1e-4f
#define BIG 1e10f
#define NRM_EPS 1e-12f

typedef float v2f __attribute__((ext_vector_type(2)));

// ---- inline-asm: 2 spheres (packed) x 2 rays (A,B) per body --------------
// Physical regs (clobbered):
//   ray A: U v[32:33], V v[34:35], BM v[36:37], DSC v[38:39], t v56,v57
//   ray B: U v[58:59], V v[60:61], BM v[62:63], DSC v[64:65], t v66,v67
//   BUF0 v[40:47] (cx2,cy2,cz2,-w2)   BUF1 v[48:55]
// Table per pair j: float4 (x0,x1,y0,y1), float4 (z0,z1,-w0,-w1), w=|c|^2-r^2.
// Rounding bit-exact to the R6-passed kernel:
//   doc = fma(dx,cx, fma(dy,cy, dz*cz));  ooc likewise
//   bm  = doc + (-od); ncv = fma(ooc,2,-oo) + (-w); dsc = fma(bm,bm,ncv)
//   t   = bm - v_sqrt(dsc); dsc<0 -> NaN -> ordered cmp false -> rejected
#define PF0 \
  "ds_read_b128 v[40:43], %[lda] offset:0\n\t" \
  "ds_read_b128 v[44:47], %[lda] offset:16\n\t" \
  "v_add_u32 %[lda], 32, %[lda]\n\t"
#define PF1 \
  "ds_read_b128 v[48:51], %[lda] offset:0\n\t" \
  "ds_read_b128 v[52:55], %[lda] offset:16\n\t" \
  "v_add_u32 %[lda], 32, %[lda]\n\t"

#define PBODY2(W, CX, CY, CZ, CWN, PF) \
  W \
  /* ray A dots */ \
  "v_pk_mul_f32 v[32:33], %[dzA], " CZ "\n\t" \
  "v_pk_mul_f32 v[34:35], %[ozA], " CZ "\n\t" \
  "v_pk_fma_f32 v[32:33], %[dyA], " CY ", v[32:33]\n\t" \
  "v_pk_fma_f32 v[34:35], %[oyA], " CY ", v[34:35]\n\t" \
  "v_pk_fma_f32 v[32:33], %[dxA], " CX ", v[32:33]\n\t" \
  "v_pk_fma_f32 v[34:35], %[oxA], " CX ", v[34:35]\n\t" \
  /* ray B dots */ \
  "v_pk_mul_f32 v[58:59], %[dzB], " CZ "\n\t" \
  "v_pk_mul_f32 v[60:61], %[ozB], " CZ "\n\t" \
  "v_pk_fma_f32 v[58:59], %[dyB], " CY ", v[58:59]\n\t" \
  "v_pk_fma_f32 v[60:61], %[oyB], " CY ", v[60:61]\n\t" \
  "v_pk_fma_f32 v[58:59], %[dxB], " CX ", v[58:59]\n\t" \
  "v_pk_fma_f32 v[60:61], %[oxB], " CX ", v[60:61]\n\t" \
  /* ray A quadratic + sqrt issue */ \
  "v_pk_add_f32 v[36:37], v[32:33], %[nodA]\n\t" \
  "v_pk_fma_f32 v[38:39], v[34:35], %[two2], %[nooA]\n\t" \
  "v_pk_add_f32 v[38:39], v[38:39], " CWN "\n\t" \
  "v_pk_fma_f32 v[38:39], v[36:37], v[36:37], v[38:39]\n\t" \
  "v_sqrt_f32 v56, v38\n\t" \
  "v_sqrt_f32 v57, v39\n\t" \
  /* ray B quadratic (hides A sqrt latency) + sqrt issue */ \
  "v_pk_add_f32 v[62:63], v[58:59], %[nodB]\n\t" \
  "v_pk_fma_f32 v[64:65], v[60:61], %[two2], %[nooB]\n\t" \
  "v_pk_add_f32 v[64:65], v[64:65], " CWN "\n\t" \
  "v_pk_fma_f32 v[64:65], v[62:63], v[62:63], v[64:65]\n\t" \
  "v_sqrt_f32 v66, v64\n\t" \
  "v_sqrt_f32 v67, v65\n\t" \
  PF \
  /* ray A select */ \
  "v_sub_f32 v56, v36, v56\n\t" \
  "v_sub_f32 v57, v37, v57\n\t" \
  "v_cmp_lt_f32 vcc, %[eps], v56\n\t" \
  "v_cmp_gt_f32 s[20:21], %[tmeA], v56\n\t" \
  "s_and_b64 vcc, vcc, s[20:21]\n\t" \
  "v_cndmask_b32 %[tmeA], %[tmeA], v56, vcc\n\t" \
  "v_cndmask_b32 %[ideA], %[ideA], %[vj], vcc\n\t" \
  "v_cmp_lt_f32 vcc, %[eps], v57\n\t" \
  "v_cmp_gt_f32 s[20:21], %[tmoA], v57\n\t" \
  "s_and_b64 vcc, vcc, s[20:21]\n\t" \
  "v_cndmask_b32 %[tmoA], %[tmoA], v57, vcc\n\t" \
  "v_cndmask_b32 %[idoA], %[idoA], %[vj], vcc\n\t" \
  /* ray B select */ \
  "v_sub_f32 v66, v62, v66\n\t" \
  "v_sub_f32 v67, v63, v67\n\t" \
  "v_cmp_lt_f32 vcc, %[eps], v66\n\t" \
  "v_cmp_gt_f32 s[20:21], %[tmeB], v66\n\t" \
  "s_and_b64 vcc, vcc, s[20:21]\n\t" \
  "v_cndmask_b32 %[tmeB], %[tmeB], v66, vcc\n\t" \
  "v_cndmask_b32 %[ideB], %[ideB], %[vj], vcc\n\t" \
  "v_cmp_lt_f32 vcc, %[eps], v67\n\t" \
  "v_cmp_gt_f32 s[20:21], %[tmoB], v67\n\t" \
  "s_and_b64 vcc, vcc, s[20:21]\n\t" \
  "v_cndmask_b32 %[tmoB], %[tmoB], v67, vcc\n\t" \
  "v_cndmask_b32 %[idoB], %[idoB], %[vj], vcc\n\t" \
  "v_add_u32 %[vj], 1, %[vj]\n\t"

__global__ __launch_bounds__(256, 4) void illum_kernel(
    const float* __restrict__ ray_o,
    const float* __restrict__ ray_d,
    const float* __restrict__ centers,
    const float* __restrict__ radii,
    const float* __restrict__ light_pos,
    const int*   __restrict__ light_idx,
    float* __restrict__ out,   // [N*3] results, then [N] active(0/1)
    int N)
{
    __shared__ float4 tab[128];   // pair j: tab[2j]=(x0,x1,y0,y1), tab[2j+1]=(z0,z1,-w0,-w1)

    const int tid = threadIdx.x;
    if (tid < 64) {
        float x0 = centers[6 * tid + 0], y0 = centers[6 * tid + 1], z0 = centers[6 * tid + 2];
        float x1 = centers[6 * tid + 3], y1 = centers[6 * tid + 4], z1 = centers[6 * tid + 5];
        float r0 = radii[2 * tid + 0],   r1 = radii[2 * tid + 1];
        float w0 = x0 * x0 + y0 * y0 + z0 * z0 - r0 * r0;
        float w1 = x1 * x1 + y1 * y1 + z1 * z1 - r1 * r1;
        tab[2 * tid + 0] = make_float4(x0, x1, y0, y1);
        tab[2 * tid + 1] = make_float4(z0, z1, -w0, -w1);
    }
    __syncthreads();

    // two rays per thread: rA = 2*ti, rB = 2*ti+1
    const int ti = blockIdx.x * blockDim.x + tid;
    const int rA = 2 * ti;
    const int rB = rA + 1;
    if (rA >= N) return;
    const bool hasB = (rB < N);

    const float2* o2 = (const float2*)ray_o;
    const float2* d2 = (const float2*)ray_d;
    float2 oa = o2[3 * ti + 0], ob = o2[3 * ti + 1], oc = o2[3 * ti + 2];
    float2 da = d2[3 * ti + 0], db = d2[3 * ti + 1], dc = d2[3 * ti + 2];

    float oxA = oa.x, oyA = oa.y, ozA = ob.x;
    float oxB = ob.y, oyB = oc.x, ozB = oc.y;
    float dxA = da.x, dyA = da.y, dzA = db.x;
    float dxB = db.y, dyB = dc.x, dzB = dc.y;

    // normalize directions (precise, once per ray)
    float dnA  = sqrtf(dxA * dxA + dyA * dyA + dzA * dzA);
    float dinA = 1.0f / fmaxf(dnA, NRM_EPS);
    dxA *= dinA; dyA *= dinA; dzA *= dinA;
    float dnB  = sqrtf(dxB * dxB + dyB * dyB + dzB * dzB);
    float dinB = 1.0f / fmaxf(dnB, NRM_EPS);
    dxB *= dinB; dyB *= dinB; dzB *= dinB;

    const float odA = oxA * dxA + oyA * dyA + ozA * dzA;
    const float ooA = oxA * oxA + oyA * oyA + ozA * ozA;
    const float odB = oxB * dxB + oyB * dyB + ozB * dzB;
    const float ooB = oxB * oxB + oyB * oyB + ozB * ozB;

    v2f dxA2 = {dxA, dxA}, dyA2 = {dyA, dyA}, dzA2 = {dzA, dzA};
    v2f oxA2 = {oxA, oxA}, oyA2 = {oyA, oyA}, ozA2 = {ozA, ozA};
    v2f nodA2 = {-odA, -odA}, nooA2 = {-ooA, -ooA};
    v2f dxB2 = {dxB, dxB}, dyB2 = {dyB, dyB}, dzB2 = {dzB, dzB};
    v2f oxB2 = {oxB, oxB}, oyB2 = {oyB, oyB}, ozB2 = {ozB, ozB};
    v2f nodB2 = {-odB, -odB}, nooB2 = {-ooB, -ooB};
    v2f two2 = {2.0f, 2.0f};

    float tmeA = BIG, tmoA = BIG, tmeB = BIG, tmoB = BIG;
    int ideA = 0, idoA = 0, ideB = 0, idoB = 0, vj = 0;
    unsigned lda = (unsigned)(size_t)&tab[0];

    asm volatile(
        "s_waitcnt lgkmcnt(0)\n\t"
        PF0
        PF1
        ".rept 31\n\t"
        PBODY2("s_waitcnt lgkmcnt(2)\n\t", "v[40:41]", "v[42:43]", "v[44:45]", "v[46:47]", PF0)
        PBODY2("s_waitcnt lgkmcnt(2)\n\t", "v[48:49]", "v[50:51]", "v[52:53]", "v[54:55]", PF1)
        ".endr\n\t"
        PBODY2("s_waitcnt lgkmcnt(2)\n\t", "v[40:41]", "v[42:43]", "v[44:45]", "v[46:47]", "")
        PBODY2("s_waitcnt lgkmcnt(0)\n\t", "v[48:49]", "v[50:51]", "v[52:53]", "v[54:55]", "")
        : [tmeA]"+v"(tmeA), [tmoA]"+v"(tmoA), [ideA]"+v"(ideA), [idoA]"+v"(idoA),
          [tmeB]"+v"(tmeB), [tmoB]"+v"(tmoB), [ideB]"+v"(ideB), [idoB]"+v"(idoB),
          [vj]"+v"(vj), [lda]"+v"(lda)
        : [dxA]"v"(dxA2), [dyA]"v"(dyA2), [dzA]"v"(dzA2),
          [oxA]"v"(oxA2), [oyA]"v"(oyA2), [ozA]"v"(ozA2),
          [nodA]"v"(nodA2), [nooA]"v"(nooA2),
          [dxB]"v"(dxB2), [dyB]"v"(dyB2), [dzB]"v"(dzB2),
          [oxB]"v"(oxB2), [oyB]"v"(oyB2), [ozB]"v"(ozB2),
          [nodB]"v"(nodB2), [nooB]"v"(nooB2),
          [two2]"v"(two2), [eps]"s"(1e-4f)
        : "v32","v33","v34","v35","v36","v37","v38","v39",
          "v40","v41","v42","v43","v44","v45","v46","v47",
          "v48","v49","v50","v51","v52","v53","v54","v55",
          "v56","v57","v58","v59","v60","v61","v62","v63",
          "v64","v65","v66","v67",
          "s20","s21","vcc","scc","memory");

    // ---- epilogue ----
    auto shade = [&](float ox, float oy, float oz, float dx, float dy, float dz,
                     float tme, float tmo, int ide, int ido, int ray, float* res) {
        // merge even/odd chains; index-aware tie-break = jnp.argmin first-occurrence
        int iE = 2 * ide, iO = 2 * ido + 1;
        bool ow = (tmo < tme) | ((tmo == tme) & (iO < iE));
        float tmin = ow ? tmo : tme;
        int   sidx = ow ? iO  : iE;
        const bool active = (tmin < BIG);

        float px = fmaf(tmin, dx, ox);
        float py = fmaf(tmin, dy, oy);
        float pz = fmaf(tmin, dz, oz);
        float4 ab = tab[2 * (sidx >> 1) + 0];
        float4 zw = tab[2 * (sidx >> 1) + 1];
        float cbx = (sidx & 1) ? ab.y : ab.x;
        float cby = (sidx & 1) ? ab.w : ab.z;
        float cbz = (sidx & 1) ? zw.y : zw.x;
        float nx = px - cbx, ny = py - cby, nz = pz - cbz;
        float nn  = sqrtf(nx * nx + ny * ny + nz * nz);
        float nin = 1.0f / fmaxf(nn, NRM_EPS);
        nx *= nin; ny *= nin; nz *= nin;
        int li = light_idx[ray];
        float dsx = light_pos[3 * li + 0] - px;
        float dsy = light_pos[3 * li + 1] - py;
        float dsz = light_pos[3 * li + 2] - pz;
        float sgn = (nz >= 0.0f) ? 1.0f : -1.0f;
        float a   = -1.0f / (sgn + nz);
        float bb  = nx * ny * a;
        float sx = 1.0f + sgn * nx * nx * a, sy = sgn * bb,          sz = -sgn * nx;
        float tx = bb,                       ty = sgn + ny * ny * a, tz = -ny;
        float l0 = dsx * sx + dsy * sy + dsz * sz;
        float l1 = dsx * tx + dsy * ty + dsz * tz;
        float l2 = dsx * nx + dsy * ny + dsz * nz;
        float ln  = sqrtf(l0 * l0 + l1 * l1 + l2 * l2);
        float lin = 1.0f / fmaxf(ln, NRM_EPS);
        res[0] = active ? ((l0 * lin + 1.0f) * 0.5f + 1.0f) * 0.5f : 0.5f;
        res[1] = active ? ((l1 * lin + 1.0f) * 0.5f + 1.0f) * 0.5f : 0.5f;
        res[2] = active ? ((l2 * lin + 1.0f) * 0.5f + 1.0f) * 0.5f : 0.5f;
        res[3] = active ? 1.0f : 0.0f;
    };

    float resA[4], resB[4] = {0.5f, 0.5f, 0.5f, 0.0f};
    shade(oxA, oyA, ozA, dxA, dyA, dzA, tmeA, tmoA, ideA, idoA, rA, resA);
    if (hasB) shade(oxB, oyB, ozB, dxB, dyB, dzB, tmeB, tmoB, ideB, idoB, rB, resB);

    float2* ro = (float2*)(out + 6 * (size_t)ti);
    ro[0] = make_float2(resA[0], resA[1]);
    if (hasB) {
        ro[1] = make_float2(resA[2], resB[0]);
        ro[2] = make_float2(resB[1], resB[2]);
        float2* ao = (float2*)(out + 3 * (size_t)N + 2 * (size_t)ti);
        ao[0] = make_float2(resA[3], resB[3]);
    } else {
        out[6 * (size_t)ti + 2] = resA[2];
        out[3 * (size_t)N + rA] = resA[3];
    }
}

extern "C" void kernel_launch(void* const* d_in, const int* in_sizes, int n_in,
                              void* d_out, int out_size, void* d_ws, size_t ws_size,
                              hipStream_t stream) {
    const float* ray_o     = (const float*)d_in[0];
    const float* ray_d     = (const float*)d_in[1];
    const float* centers   = (const float*)d_in[2];
    const float* radii     = (const float*)d_in[3];
    const float* light_pos = (const float*)d_in[4];
    const int*   light_idx = (const int*)d_in[5];
    float* out = (float*)d_out;

    const int N = in_sizes[0] / 3;   // S fixed at 128

    const int NP = (N + 1) / 2;
    const int block = 256;
    const int grid  = (NP + block - 1) / block;
    illum_kernel<<<grid, block, 0, stream>>>(ray_o, ray_d, centers, radii,
                                             light_pos, light_idx, out, N);
}